// Round 7
// baseline (4045.374 us; speedup 1.0000x reference)
//
#include <hip/hip_runtime.h>
#include <math.h>

#define NB 512
#define NT 128
#define NN 18
#define NDIM 32
#define NHID 64

typedef _Float16 half_t;
typedef _Float16 f16x4 __attribute__((ext_vector_type(4)));
typedef _Float16 f16x8 __attribute__((ext_vector_type(8)));
typedef float    f32x4 __attribute__((ext_vector_type(4)));

__device__ __forceinline__ float fast_sigmoid(float x) {
    return __builtin_amdgcn_rcpf(1.f + __expf(-x));
}
__device__ __forceinline__ float fast_tanh(float x) {
    float xc = fminf(fmaxf(x, -15.f), 15.f);
    float e  = __expf(2.f * xc);
    return 1.f - 2.f * __builtin_amdgcn_rcpf(e + 1.f);
}
__device__ __forceinline__ f32x4 mfma16(f16x8 a, f16x8 b, f32x4 c) {
    return __builtin_amdgcn_mfma_f32_16x16x32_f16(a, b, c, 0, 0, 0);
}

// ---------------------------------------------------------------------------
// MM1 (round-7 = round-6 with DEPTH trimmed for 2-block residency): fully
// unrolled, statically indexed B array, loads hoisted DEPTH columns ahead.
// Live set: DEPTH*KT*4 (B) + 2*KT*4 (A) + 8 (acc). DEPTH: KT=3 -> 4 (was 5;
// -12 regs peak), KT=4 -> 3. Round-6 lesson: VGPR_Count=128 is arch-only;
// AGPR accumulators pushed the unified total past 128 -> only 1 block/CU
// resident (Occupancy 23.5%). waves_per_eu(4) + this trim target 16 waves.
// SCATTER RULE (race fix): mt=0 writes rows 0..15 (all quads); mt=1 writes
// ONLY quad==0 (rows 16..19). Rows 20..23 / 120..127 stay zero from init.
// ---------------------------------------------------------------------------
template <int KT, int CNT, int NCS>
__device__ __forceinline__ void mm1_u(const f16x8* __restrict__ Wf, int NTW,
                                      const half_t* Zf, half_t* Yf,
                                      int nt0, int lane) {
    constexpr int DEPTH = (CNT < 3) ? CNT : (KT == 3 ? ((CNT > 4) ? 4 : CNT) : 3);
    f16x8 A[2 * KT];
#pragma unroll
    for (int kt = 0; kt < KT; ++kt) {
        A[kt * 2 + 0] = *(const f16x8*)(Zf + (kt * 2 + 0) * 512 + lane * 8);
        A[kt * 2 + 1] = *(const f16x8*)(Zf + (kt * 2 + 1) * 512 + lane * 8);
    }
    f16x8 B[CNT][KT];
#pragma unroll
    for (int i = 0; i < DEPTH; ++i)
#pragma unroll
        for (int kt = 0; kt < KT; ++kt)
            B[i][kt] = Wf[(kt * NTW + nt0 + i) * 64 + lane];

    const int quad = lane >> 4, ln = lane & 15;
#pragma unroll
    for (int i = 0; i < CNT; ++i) {
        if (i + DEPTH < CNT) {   // compile-time under full unroll
#pragma unroll
            for (int kt = 0; kt < KT; ++kt)
                B[i + DEPTH][kt] = Wf[(kt * NTW + nt0 + i + DEPTH) * 64 + lane];
        }
        const int ntp = nt0 + i;
        f32x4 ac0 = {0.f, 0.f, 0.f, 0.f};
        f32x4 ac1 = {0.f, 0.f, 0.f, 0.f};
#pragma unroll
        for (int kt = 0; kt < KT; ++kt) {
            ac0 = mfma16(A[kt * 2 + 0], B[i][kt], ac0);
            ac1 = mfma16(A[kt * 2 + 1], B[i][kt], ac1);
        }
        const int m  = ntp >> NCS;            // ncol16 = 1<<NCS
        const int ot = ntp - (m << NCS);
        // mt=0: rows k = 24m + quad*4 + r (0..15)
        {
            const int k0 = 24 * m + quad * 4;
            f16x4 pk;
#pragma unroll
            for (int r = 0; r < 4; ++r) pk[r] = (half_t)ac0[r];
            *(f16x4*)(Yf + ((k0 >> 5) * 8 + ot) * 512 +
                      (((((k0 >> 3) & 3) << 4) | ln) * 8) + (k0 & 7)) = pk;
        }
        // mt=1: only quad 0 -> rows 16..19 (16,17 real; 18,19 zero)
        if (quad == 0) {
            const int k0 = 24 * m + 16;       // multiple of 8
            f16x4 pk;
#pragma unroll
            for (int r = 0; r < 4; ++r) pk[r] = (half_t)ac1[r];
            *(f16x4*)(Yf + ((k0 >> 5) * 8 + ot) * 512 +
                      (((((k0 >> 3) & 3) << 4) | ln) * 8) + (k0 & 7)) = pk;
        }
    }
}

// ---------------------------------------------------------------------------
// MM2 gate: ru(18 x 128) = Pcat(18 x 120pad128) * Ycat + bias -> sigmoid.
// o<64: r -> write r*h into Z frags (kZ = DIMin+o); o>=64: u -> ubuf.
// Does NOT read Zf (safe to write).
// ---------------------------------------------------------------------------
__device__ __forceinline__ void mm2_gate(const half_t* Pc, const half_t* Yf,
                                         half_t* Zf, float bias,
                                         const float (*h)[NHID], float (*ub)[NHID],
                                         int DIMin, int wv, int lane) {
    const int nt2 = wv, quad = lane >> 4, ln = lane & 15;
    f32x4 a0 = {0.f, 0.f, 0.f, 0.f};
    f32x4 a1 = {0.f, 0.f, 0.f, 0.f};
#pragma unroll
    for (int kt = 0; kt < 4; ++kt) {
        f16x8 B  = *(const f16x8*)(Yf + (kt * 8 + nt2) * 512 + lane * 8);
        f16x8 A0 = *(const f16x8*)(Pc + (kt * 2 + 0) * 512 + lane * 8);
        f16x8 A1 = *(const f16x8*)(Pc + (kt * 2 + 1) * 512 + lane * 8);
        a0 = mfma16(A0, B, a0);
        a1 = mfma16(A1, B, a1);
    }
    const int o = nt2 * 16 + ln;
    if (o < NHID) {
        const int kZ = DIMin + o;
        const int base = ((kZ >> 5) * 2) * 512 + (((kZ >> 3) & 3) << 4) * 8 + (kZ & 7);
#pragma unroll
        for (int r = 0; r < 4; ++r) {
            int n = quad * 4 + r;
            float rv = fast_sigmoid(a0[r] + bias);
            Zf[base + (n & 15) * 8] = (half_t)(rv * h[n][o]);
        }
        if (quad == 0) {
#pragma unroll
            for (int r = 0; r < 2; ++r) {
                int n = 16 + r;
                float rv = fast_sigmoid(a1[r] + bias);
                Zf[base + 512 + (n & 15) * 8] = (half_t)(rv * h[n][o]);
            }
        }
    } else {
        const int oc = o - NHID;
#pragma unroll
        for (int r = 0; r < 4; ++r) ub[quad * 4 + r][oc] = fast_sigmoid(a0[r] + bias);
        if (quad == 0) {
#pragma unroll
            for (int r = 0; r < 2; ++r) ub[16 + r][oc] = fast_sigmoid(a1[r] + bias);
        }
    }
}

// ---------------------------------------------------------------------------
// MM2 cand: c = tanh(Pcat * Ycat + bias); h = u*h + (1-u)*c.
// Wave w: nt2 = w&3, mtA = w>>2.
// ---------------------------------------------------------------------------
__device__ __forceinline__ void mm2_cand(const half_t* Pc, const half_t* Yf,
                                         float bias, float (*h)[NHID],
                                         const float (*ub)[NHID], int wv, int lane) {
    const int nt2 = wv & 3, mtA = wv >> 2;
    const int quad = lane >> 4;
    f32x4 a = {0.f, 0.f, 0.f, 0.f};
#pragma unroll
    for (int kt = 0; kt < 4; ++kt) {
        f16x8 B = *(const f16x8*)(Yf + (kt * 8 + nt2) * 512 + lane * 8);
        f16x8 A = *(const f16x8*)(Pc + (kt * 2 + mtA) * 512 + lane * 8);
        a = mfma16(A, B, a);
    }
    const int o = nt2 * 16 + (lane & 15);
#pragma unroll
    for (int r = 0; r < 4; ++r) {
        int n = mtA * 16 + quad * 4 + r;
        if (n < NN) {
            float cv = fast_tanh(a[r] + bias);
            float uv = ub[n][o];
            h[n][o] = uv * h[n][o] + (1.f - uv) * cv;
        }
    }
}

// ---------------------------------------------------------------------------
// Weight pack: W[(m*C + c)][o] fp32 -> MM1 B-frag order fp16.
// ---------------------------------------------------------------------------
__global__ void pack_w(const float* __restrict__ W, f16x8* __restrict__ out,
                       int KT, int NTW, int ncol, int C) {
    int idx = blockIdx.x * blockDim.x + threadIdx.x;
    if (idx >= KT * NTW * 64) return;
    int lane = idx & 63, f = idx >> 6;
    int kt = f / NTW, ntp = f - kt * NTW;
    int ncol16 = ncol >> 4;
    int m = ntp / ncol16, ot = ntp - m * ncol16;
    int o = ot * 16 + (lane & 15);
    f16x8 v;
#pragma unroll
    for (int jj = 0; jj < 8; ++jj) {
        int c = kt * 32 + ((lane >> 4) << 3) + jj;
        v[jj] = (half_t)W[(m * C + c) * ncol + o];
    }
    out[idx] = v;
}

// ---------------------------------------------------------------------------
// Pcat pack: A-frag order fp16 for MM2.
// ---------------------------------------------------------------------------
__global__ void pack_pcat(const float* __restrict__ sup, f16x8* __restrict__ out) {
    int tid = threadIdx.x;                 // 512 threads, 1 block
    int lane = tid & 63, fidx = tid >> 6;  // 8 frags: (kt2, mtA)
    int mtA = fidx & 1, kt2 = fidx >> 1;
    int n = mtA * 16 + (lane & 15);
    f16x8 v;
#pragma unroll 1
    for (int jj = 0; jj < 8; ++jj) {
        int k = kt2 * 32 + ((lane >> 4) << 3) + jj;
        int m = k / 24, j = k - m * 24;
        float val = 0.f;
        if (n < NN && j < NN && m < 5) {
            if (m == 0)      val = (n == j) ? 1.f : 0.f;
            else if (m == 1) val = sup[0 * 324 + n * 18 + j];
            else if (m == 3) val = sup[1 * 324 + n * 18 + j];
            else {
                const float* S = sup + ((m == 2) ? 0 : 1) * 324;
                float acc = 0.f;
                for (int l = 0; l < NN; ++l) acc += S[n * 18 + l] * S[l * 18 + j];
                val = 2.f * acc - ((n == j) ? 1.f : 0.f);
            }
        }
        v[jj] = (half_t)val;
    }
    out[fidx * 64 + lane] = v;
}

// ---------------------------------------------------------------------------
// Persistent per-batch kernel: 512 blocks x 512 threads (8 waves).
// LDS: Zf 8K + Yf 32K + Pc 8K + h_a/h_b/ubuf 13.5K = 62.9K -> 2 blocks/CU
// by LDS. amdgpu_waves_per_eu(4,8): unified VGPR+AGPR budget <= 512/4 = 128
// per wave so 16 waves (2 blocks) actually FIT (r6 lesson: arch-VGPR 128 +
// AGPR accumulators exceeded the pool -> 1 block/CU, Occupancy 23.5%).
// ---------------------------------------------------------------------------
__global__ __launch_bounds__(512)
__attribute__((amdgpu_waves_per_eu(4, 8))) void dcrnn_kernel(
    const float* __restrict__ x,
    const f16x8* __restrict__ wg0, const float* __restrict__ bg0,
    const f16x8* __restrict__ wc0, const float* __restrict__ bc0,
    const f16x8* __restrict__ wg1, const float* __restrict__ bg1,
    const f16x8* __restrict__ wc1, const float* __restrict__ bc1,
    const f16x8* __restrict__ Pf,
    const float* __restrict__ fcw, const float* __restrict__ fcb,
    float* __restrict__ out) {
    __shared__ __align__(16) half_t Zf[8 * 512];    // Z as A-frags (kt*2+mt)
    __shared__ __align__(16) half_t Yf[32 * 512];   // Ycat as B-frags (kt2*8+ot)
    __shared__ __align__(16) half_t Pc[8 * 512];    // Pcat as A-frags
    __shared__ float h_a[NN][NHID];
    __shared__ float h_b[NN][NHID];
    __shared__ float ubuf[NN][NHID];

    const int tid  = threadIdx.x;
    const int lane = tid & 63;
    const int wv   = tid >> 6;
    const int b    = blockIdx.x;

    // one-time init: zero Z/Y frag pads (pad stays zero forever), load Pcat, zero h
    {
        f16x8 z = {0, 0, 0, 0, 0, 0, 0, 0};
        ((f16x8*)Zf)[tid] = z;
#pragma unroll
        for (int i = 0; i < 4; ++i) ((f16x8*)Yf)[tid + i * 512] = z;
        ((f16x8*)Pc)[tid] = Pf[tid];
        for (int i = tid; i < NN * NHID; i += 512) {
            ((float*)h_a)[i] = 0.f;
            ((float*)h_b)[i] = 0.f;
        }
    }

    // mm1 wave partitions: gate NTW=40 -> 5/wave; cand NTW=20 -> 3,3,3,3,2,2,2,2
    const int gnt0 = wv * 5;
    const int cnt0 = (wv < 4) ? wv * 3 : 12 + (wv - 4) * 2;
    const int ln   = lane & 15;

    const float bgt0 = bg0[wv * 16 + ln];
    const float bct0 = bc0[(wv & 3) * 16 + ln];
    const float bgt1 = bg1[wv * 16 + ln];
    const float bct1 = bc1[(wv & 3) * 16 + ln];

    __syncthreads();

    const float* xb = x + (size_t)b * NT * NN * NDIM;

    for (int t = 0; t < NT; ++t) {
        const float* xt = xb + (size_t)t * NN * NDIM;

        // ======== layer 0: C=96 (KT=3), DIMin=32 ========
        // stage A: Zf <- [x | h_a]
        for (int idx = tid; idx < NN * 12; idx += 512) {
            int n = idx / 12, c8 = idx - n * 12;
            int c = c8 * 8;
            const float* src = (c < NDIM) ? &xt[n * NDIM + c] : &h_a[n][c - NDIM];
            f16x8 o8;
#pragma unroll
            for (int q = 0; q < 8; ++q) o8[q] = (half_t)src[q];
            *(f16x8*)(Zf + ((c8 >> 2) * 2 + (n >> 4)) * 512 +
                      (((c8 & 3) << 4) | (n & 15)) * 8) = o8;
        }
        __syncthreads();
        mm1_u<3, 5, 3>(wg0, 40, Zf, Yf, gnt0, lane);
        __syncthreads();
        mm2_gate(Pc, Yf, Zf, bgt0, h_a, ubuf, 32, wv, lane);
        __syncthreads();
        if (wv < 4) mm1_u<3, 3, 2>(wc0, 20, Zf, Yf, cnt0, lane);
        else        mm1_u<3, 2, 2>(wc0, 20, Zf, Yf, cnt0, lane);
        __syncthreads();
        mm2_cand(Pc, Yf, bct0, h_a, ubuf, wv, lane);
        __syncthreads();

        // ======== layer 1: C=128 (KT=4), DIMin=64 ========
        for (int idx = tid; idx < NN * 16; idx += 512) {
            int n = idx >> 4, c8 = idx & 15;
            int c = c8 * 8;
            const float* src = (c < NHID) ? &h_a[n][c] : &h_b[n][c - NHID];
            f16x8 o8;
#pragma unroll
            for (int q = 0; q < 8; ++q) o8[q] = (half_t)src[q];
            *(f16x8*)(Zf + ((c8 >> 2) * 2 + (n >> 4)) * 512 +
                      (((c8 & 3) << 4) | (n & 15)) * 8) = o8;
        }
        __syncthreads();
        mm1_u<4, 5, 3>(wg1, 40, Zf, Yf, gnt0, lane);
        __syncthreads();
        mm2_gate(Pc, Yf, Zf, bgt1, h_b, ubuf, 64, wv, lane);
        __syncthreads();
        if (wv < 4) mm1_u<4, 3, 2>(wc1, 20, Zf, Yf, cnt0, lane);
        else        mm1_u<4, 2, 2>(wc1, 20, Zf, Yf, cnt0, lane);
        __syncthreads();
        mm2_cand(Pc, Yf, bct1, h_b, ubuf, wv, lane);
        __syncthreads();
    }

    // ---- output head: out[b] = max_n (relu(h_b[n]) . fcw + fcb) ----
    if (tid < NN) {
        float acc = fcb[0];
#pragma unroll 1
        for (int c = 0; c < NHID; ++c)
            acc = fmaf(fmaxf(h_b[tid][c], 0.f), fcw[c], acc);
        ((float*)ubuf)[tid] = acc;
    }
    __syncthreads();
    if (tid == 0) {
        float m = -1e30f;
#pragma unroll
        for (int n = 0; n < NN; ++n) m = fmaxf(m, ((float*)ubuf)[n]);
        out[b] = m;
    }
}

extern "C" void kernel_launch(void* const* d_in, const int* in_sizes, int n_in,
                              void* d_out, int out_size, void* d_ws, size_t ws_size,
                              hipStream_t stream) {
    const float* x   = (const float*)d_in[0];
    const float* sup = (const float*)d_in[1];
    const float* wg0 = (const float*)d_in[2];
    const float* bg0 = (const float*)d_in[3];
    const float* wc0 = (const float*)d_in[4];
    const float* bc0 = (const float*)d_in[5];
    const float* wg1 = (const float*)d_in[6];
    const float* bg1 = (const float*)d_in[7];
    const float* wc1 = (const float*)d_in[8];
    const float* bc1 = (const float*)d_in[9];
    const float* fcw = (const float*)d_in[10];
    const float* fcb = (const float*)d_in[11];
    float* out = (float*)d_out;

    // ws: packed fp16 MM1 B-frags + Pcat A-frags (438272 B total)
    char* ws = (char*)d_ws;
    f16x8* wg0p = (f16x8*)(ws + 0);        // KT=3, NTW=40 -> 122880 B
    f16x8* wc0p = (f16x8*)(ws + 122880);   // KT=3, NTW=20 ->  61440 B
    f16x8* wg1p = (f16x8*)(ws + 184320);   // KT=4, NTW=40 -> 163840 B
    f16x8* wc1p = (f16x8*)(ws + 348160);   // KT=4, NTW=20 ->  81920 B
    f16x8* pfp  = (f16x8*)(ws + 430080);   // 8 frags      ->   8192 B

    pack_w<<<dim3(30), dim3(256), 0, stream>>>(wg0, wg0p, 3, 40, 128, 96);
    pack_w<<<dim3(15), dim3(256), 0, stream>>>(wc0, wc0p, 3, 20, 64, 96);
    pack_w<<<dim3(40), dim3(256), 0, stream>>>(wg1, wg1p, 4, 40, 128, 128);
    pack_w<<<dim3(20), dim3(256), 0, stream>>>(wc1, wc1p, 4, 20, 64, 128);
    pack_pcat<<<dim3(1), dim3(512), 0, stream>>>(sup, pfp);

    dcrnn_kernel<<<dim3(NB), dim3(512), 0, stream>>>(
        x, wg0p, bg0, wc0p, bc0, wg1p, bg1, wc1p, bc1, pfp, fcw, fcb, out);
}

// Round 8
// 2694.870 us; speedup vs baseline: 1.5011x; 1.5011x over previous
//
#include <hip/hip_runtime.h>
#include <math.h>

#define NB 512
#define NT 128
#define NN 18
#define NDIM 32
#define NHID 64

typedef _Float16 half_t;
typedef _Float16 f16x4 __attribute__((ext_vector_type(4)));
typedef _Float16 f16x8 __attribute__((ext_vector_type(8)));
typedef float    f32x4 __attribute__((ext_vector_type(4)));

__device__ __forceinline__ float fast_sigmoid(float x) {
    return __builtin_amdgcn_rcpf(1.f + __expf(-x));
}
__device__ __forceinline__ float fast_tanh(float x) {
    float xc = fminf(fmaxf(x, -15.f), 15.f);
    float e  = __expf(2.f * xc);
    return 1.f - 2.f * __builtin_amdgcn_rcpf(e + 1.f);
}
__device__ __forceinline__ f32x4 mfma16(f16x8 a, f16x8 b, f32x4 c) {
    return __builtin_amdgcn_mfma_f32_16x16x32_f16(a, b, c, 0, 0, 0);
}

// ---------------------------------------------------------------------------
// Register-cap model (established r5-r7): launch_bounds arg2 = min BLOCKS/CU;
// cap = 2048 unified regs / (arg2 * 8 waves). arg2=4 -> 64 (r0-r5 spills),
// arg2=2 -> 128+accum (r6, 2492us, 1 block/CU resident anyway), arg2=1 ->
// 256/wave. We can't fit 2 blocks (demand ~160), so take the 256 cap and
// make the GATE weights (Bg0 60 + Bg1 80 regs) PERSISTENT across the t-loop
// -- deletes 35 of 56 in-loop weight loads/wave/step. r1's version of this
// failed only because the cap was 64 then.
// ---------------------------------------------------------------------------

// MM1 with persistent B (gate): B held in registers across the whole t-loop.
// SCATTER RULE (race fix): mt=0 writes rows 0..15 (all quads); mt=1 writes
// ONLY quad==0 (rows 16..19). Rows 20..23 / 120..127 stay zero from init.
template <int KT, int CNT, int NCS>
__device__ __forceinline__ void mm1_p(const f16x8 (&B)[CNT][KT],
                                      const half_t* Zf, half_t* Yf,
                                      int nt0, int lane) {
    f16x8 A[2 * KT];
#pragma unroll
    for (int kt = 0; kt < KT; ++kt) {
        A[kt * 2 + 0] = *(const f16x8*)(Zf + (kt * 2 + 0) * 512 + lane * 8);
        A[kt * 2 + 1] = *(const f16x8*)(Zf + (kt * 2 + 1) * 512 + lane * 8);
    }
    const int quad = lane >> 4, ln = lane & 15;
#pragma unroll
    for (int i = 0; i < CNT; ++i) {
        const int ntp = nt0 + i;
        f32x4 ac0 = {0.f, 0.f, 0.f, 0.f};
        f32x4 ac1 = {0.f, 0.f, 0.f, 0.f};
#pragma unroll
        for (int kt = 0; kt < KT; ++kt) {
            ac0 = mfma16(A[kt * 2 + 0], B[i][kt], ac0);
            ac1 = mfma16(A[kt * 2 + 1], B[i][kt], ac1);
        }
        const int m  = ntp >> NCS;            // ncol16 = 1<<NCS
        const int ot = ntp - (m << NCS);
        {
            const int k0 = 24 * m + quad * 4;
            f16x4 pk;
#pragma unroll
            for (int r = 0; r < 4; ++r) pk[r] = (half_t)ac0[r];
            *(f16x4*)(Yf + ((k0 >> 5) * 8 + ot) * 512 +
                      (((((k0 >> 3) & 3) << 4) | ln) * 8) + (k0 & 7)) = pk;
        }
        if (quad == 0) {
            const int k0 = 24 * m + 16;       // multiple of 8
            f16x4 pk;
#pragma unroll
            for (int r = 0; r < 4; ++r) pk[r] = (half_t)ac1[r];
            *(f16x4*)(Yf + ((k0 >> 5) * 8 + ot) * 512 +
                      (((((k0 >> 3) & 3) << 4) | ln) * 8) + (k0 & 7)) = pk;
        }
    }
}

// MM1 streamed (cand): r6 version, all CNT(<=3) columns loaded upfront
// within the phase (transient regs only).
template <int KT, int CNT, int NCS>
__device__ __forceinline__ void mm1_u(const f16x8* __restrict__ Wf, int NTW,
                                      const half_t* Zf, half_t* Yf,
                                      int nt0, int lane) {
    f16x8 B[CNT][KT];
#pragma unroll
    for (int i = 0; i < CNT; ++i)
#pragma unroll
        for (int kt = 0; kt < KT; ++kt)
            B[i][kt] = Wf[(kt * NTW + nt0 + i) * 64 + lane];
    mm1_p<KT, CNT, NCS>(B, Zf, Yf, nt0, lane);
}

// ---------------------------------------------------------------------------
// MM2 gate: ru(18 x 128) = Pcat(18 x 120pad128) * Ycat + bias -> sigmoid.
// o<64: r -> write r*h into Z frags (kZ = DIMin+o); o>=64: u -> ubuf.
// Does NOT read Zf (safe to write).
// ---------------------------------------------------------------------------
__device__ __forceinline__ void mm2_gate(const half_t* Pc, const half_t* Yf,
                                         half_t* Zf, float bias,
                                         const float (*h)[NHID], float (*ub)[NHID],
                                         int DIMin, int wv, int lane) {
    const int nt2 = wv, quad = lane >> 4, ln = lane & 15;
    f32x4 a0 = {0.f, 0.f, 0.f, 0.f};
    f32x4 a1 = {0.f, 0.f, 0.f, 0.f};
#pragma unroll
    for (int kt = 0; kt < 4; ++kt) {
        f16x8 B  = *(const f16x8*)(Yf + (kt * 8 + nt2) * 512 + lane * 8);
        f16x8 A0 = *(const f16x8*)(Pc + (kt * 2 + 0) * 512 + lane * 8);
        f16x8 A1 = *(const f16x8*)(Pc + (kt * 2 + 1) * 512 + lane * 8);
        a0 = mfma16(A0, B, a0);
        a1 = mfma16(A1, B, a1);
    }
    const int o = nt2 * 16 + ln;
    if (o < NHID) {
        const int kZ = DIMin + o;
        const int base = ((kZ >> 5) * 2) * 512 + (((kZ >> 3) & 3) << 4) * 8 + (kZ & 7);
#pragma unroll
        for (int r = 0; r < 4; ++r) {
            int n = quad * 4 + r;
            float rv = fast_sigmoid(a0[r] + bias);
            Zf[base + (n & 15) * 8] = (half_t)(rv * h[n][o]);
        }
        if (quad == 0) {
#pragma unroll
            for (int r = 0; r < 2; ++r) {
                int n = 16 + r;
                float rv = fast_sigmoid(a1[r] + bias);
                Zf[base + 512 + (n & 15) * 8] = (half_t)(rv * h[n][o]);
            }
        }
    } else {
        const int oc = o - NHID;
#pragma unroll
        for (int r = 0; r < 4; ++r) ub[quad * 4 + r][oc] = fast_sigmoid(a0[r] + bias);
        if (quad == 0) {
#pragma unroll
            for (int r = 0; r < 2; ++r) ub[16 + r][oc] = fast_sigmoid(a1[r] + bias);
        }
    }
}

// ---------------------------------------------------------------------------
// MM2 cand: c = tanh(Pcat * Ycat + bias); h = u*h + (1-u)*c.
// Wave w: nt2 = w&3, mtA = w>>2.
// ---------------------------------------------------------------------------
__device__ __forceinline__ void mm2_cand(const half_t* Pc, const half_t* Yf,
                                         float bias, float (*h)[NHID],
                                         const float (*ub)[NHID], int wv, int lane) {
    const int nt2 = wv & 3, mtA = wv >> 2;
    const int quad = lane >> 4;
    f32x4 a = {0.f, 0.f, 0.f, 0.f};
#pragma unroll
    for (int kt = 0; kt < 4; ++kt) {
        f16x8 B = *(const f16x8*)(Yf + (kt * 8 + nt2) * 512 + lane * 8);
        f16x8 A = *(const f16x8*)(Pc + (kt * 2 + mtA) * 512 + lane * 8);
        a = mfma16(A, B, a);
    }
    const int o = nt2 * 16 + (lane & 15);
#pragma unroll
    for (int r = 0; r < 4; ++r) {
        int n = mtA * 16 + quad * 4 + r;
        if (n < NN) {
            float cv = fast_tanh(a[r] + bias);
            float uv = ub[n][o];
            h[n][o] = uv * h[n][o] + (1.f - uv) * cv;
        }
    }
}

// ---------------------------------------------------------------------------
// Weight pack: W[(m*C + c)][o] fp32 -> MM1 B-frag order fp16.
// ---------------------------------------------------------------------------
__global__ void pack_w(const float* __restrict__ W, f16x8* __restrict__ out,
                       int KT, int NTW, int ncol, int C) {
    int idx = blockIdx.x * blockDim.x + threadIdx.x;
    if (idx >= KT * NTW * 64) return;
    int lane = idx & 63, f = idx >> 6;
    int kt = f / NTW, ntp = f - kt * NTW;
    int ncol16 = ncol >> 4;
    int m = ntp / ncol16, ot = ntp - m * ncol16;
    int o = ot * 16 + (lane & 15);
    f16x8 v;
#pragma unroll
    for (int jj = 0; jj < 8; ++jj) {
        int c = kt * 32 + ((lane >> 4) << 3) + jj;
        v[jj] = (half_t)W[(m * C + c) * ncol + o];
    }
    out[idx] = v;
}

// ---------------------------------------------------------------------------
// Pcat pack: A-frag order fp16 for MM2.
// ---------------------------------------------------------------------------
__global__ void pack_pcat(const float* __restrict__ sup, f16x8* __restrict__ out) {
    int tid = threadIdx.x;                 // 512 threads, 1 block
    int lane = tid & 63, fidx = tid >> 6;  // 8 frags: (kt2, mtA)
    int mtA = fidx & 1, kt2 = fidx >> 1;
    int n = mtA * 16 + (lane & 15);
    f16x8 v;
#pragma unroll 1
    for (int jj = 0; jj < 8; ++jj) {
        int k = kt2 * 32 + ((lane >> 4) << 3) + jj;
        int m = k / 24, j = k - m * 24;
        float val = 0.f;
        if (n < NN && j < NN && m < 5) {
            if (m == 0)      val = (n == j) ? 1.f : 0.f;
            else if (m == 1) val = sup[0 * 324 + n * 18 + j];
            else if (m == 3) val = sup[1 * 324 + n * 18 + j];
            else {
                const float* S = sup + ((m == 2) ? 0 : 1) * 324;
                float acc = 0.f;
                for (int l = 0; l < NN; ++l) acc += S[n * 18 + l] * S[l * 18 + j];
                val = 2.f * acc - ((n == j) ? 1.f : 0.f);
            }
        }
        v[jj] = (half_t)val;
    }
    out[fidx * 64 + lane] = v;
}

// ---------------------------------------------------------------------------
// Persistent per-batch kernel: 512 blocks x 512 threads (8 waves).
// LDS: Zf 8K + Yf 32K + Pc 8K + h_a/h_b/ubuf 13.5K = 62.9K.
// __launch_bounds__(512, 1): unified reg cap 256/wave (we run 1 block/CU
// regardless -- r6 showed 16 waves can't fit the ~160-reg demand). The
// headroom holds Bg0 (60) + Bg1 (80) persistent across the t-loop.
// ---------------------------------------------------------------------------
__global__ __launch_bounds__(512, 1) void dcrnn_kernel(
    const float* __restrict__ x,
    const f16x8* __restrict__ wg0, const float* __restrict__ bg0,
    const f16x8* __restrict__ wc0, const float* __restrict__ bc0,
    const f16x8* __restrict__ wg1, const float* __restrict__ bg1,
    const f16x8* __restrict__ wc1, const float* __restrict__ bc1,
    const f16x8* __restrict__ Pf,
    const float* __restrict__ fcw, const float* __restrict__ fcb,
    float* __restrict__ out) {
    __shared__ __align__(16) half_t Zf[8 * 512];    // Z as A-frags (kt*2+mt)
    __shared__ __align__(16) half_t Yf[32 * 512];   // Ycat as B-frags (kt2*8+ot)
    __shared__ __align__(16) half_t Pc[8 * 512];    // Pcat as A-frags
    __shared__ float h_a[NN][NHID];
    __shared__ float h_b[NN][NHID];
    __shared__ float ubuf[NN][NHID];

    const int tid  = threadIdx.x;
    const int lane = tid & 63;
    const int wv   = tid >> 6;
    const int b    = blockIdx.x;

    // one-time init: zero Z/Y frag pads (pad stays zero forever), load Pcat, zero h
    {
        f16x8 z = {0, 0, 0, 0, 0, 0, 0, 0};
        ((f16x8*)Zf)[tid] = z;
#pragma unroll
        for (int i = 0; i < 4; ++i) ((f16x8*)Yf)[tid + i * 512] = z;
        ((f16x8*)Pc)[tid] = Pf[tid];
        for (int i = tid; i < NN * NHID; i += 512) {
            ((float*)h_a)[i] = 0.f;
            ((float*)h_b)[i] = 0.f;
        }
    }

    // mm1 wave partitions: gate NTW=40 -> 5/wave; cand NTW=20 -> 3,3,3,3,2,2,2,2
    const int gnt0 = wv * 5;
    const int cnt0 = (wv < 4) ? wv * 3 : 12 + (wv - 4) * 2;
    const int ln   = lane & 15;

    const float bgt0 = bg0[wv * 16 + ln];
    const float bct0 = bc0[(wv & 3) * 16 + ln];
    const float bgt1 = bg1[wv * 16 + ln];
    const float bct1 = bc1[(wv & 3) * 16 + ln];

    // ---- persistent gate-weight registers (t-invariant; cap 256 makes this
    // hold -- r1's failure was the 64-reg cap, not the idea) ----
    f16x8 Bg0[5][3];
#pragma unroll
    for (int i = 0; i < 5; ++i)
#pragma unroll
        for (int kt = 0; kt < 3; ++kt)
            Bg0[i][kt] = wg0[(kt * 40 + gnt0 + i) * 64 + lane];
    f16x8 Bg1[5][4];
#pragma unroll
    for (int i = 0; i < 5; ++i)
#pragma unroll
        for (int kt = 0; kt < 4; ++kt)
            Bg1[i][kt] = wg1[(kt * 40 + gnt0 + i) * 64 + lane];

    __syncthreads();

    const float* xb = x + (size_t)b * NT * NN * NDIM;

    for (int t = 0; t < NT; ++t) {
        const float* xt = xb + (size_t)t * NN * NDIM;

        // ======== layer 0: C=96 (KT=3), DIMin=32 ========
        // stage A: Zf <- [x | h_a]
        for (int idx = tid; idx < NN * 12; idx += 512) {
            int n = idx / 12, c8 = idx - n * 12;
            int c = c8 * 8;
            const float* src = (c < NDIM) ? &xt[n * NDIM + c] : &h_a[n][c - NDIM];
            f16x8 o8;
#pragma unroll
            for (int q = 0; q < 8; ++q) o8[q] = (half_t)src[q];
            *(f16x8*)(Zf + ((c8 >> 2) * 2 + (n >> 4)) * 512 +
                      (((c8 & 3) << 4) | (n & 15)) * 8) = o8;
        }
        __syncthreads();
        mm1_p<3, 5, 3>(Bg0, Zf, Yf, gnt0, lane);
        __syncthreads();
        mm2_gate(Pc, Yf, Zf, bgt0, h_a, ubuf, 32, wv, lane);
        __syncthreads();
        if (wv < 4) mm1_u<3, 3, 2>(wc0, 20, Zf, Yf, cnt0, lane);
        else        mm1_u<3, 2, 2>(wc0, 20, Zf, Yf, cnt0, lane);
        __syncthreads();
        mm2_cand(Pc, Yf, bct0, h_a, ubuf, wv, lane);
        __syncthreads();

        // ======== layer 1: C=128 (KT=4), DIMin=64 ========
        for (int idx = tid; idx < NN * 16; idx += 512) {
            int n = idx >> 4, c8 = idx & 15;
            int c = c8 * 8;
            const float* src = (c < NHID) ? &h_a[n][c] : &h_b[n][c - NHID];
            f16x8 o8;
#pragma unroll
            for (int q = 0; q < 8; ++q) o8[q] = (half_t)src[q];
            *(f16x8*)(Zf + ((c8 >> 2) * 2 + (n >> 4)) * 512 +
                      (((c8 & 3) << 4) | (n & 15)) * 8) = o8;
        }
        __syncthreads();
        mm1_p<4, 5, 3>(Bg1, Zf, Yf, gnt0, lane);
        __syncthreads();
        mm2_gate(Pc, Yf, Zf, bgt1, h_b, ubuf, 64, wv, lane);
        __syncthreads();
        if (wv < 4) mm1_u<4, 3, 2>(wc1, 20, Zf, Yf, cnt0, lane);
        else        mm1_u<4, 2, 2>(wc1, 20, Zf, Yf, cnt0, lane);
        __syncthreads();
        mm2_cand(Pc, Yf, bct1, h_b, ubuf, wv, lane);
        __syncthreads();
    }

    // ---- output head: out[b] = max_n (relu(h_b[n]) . fcw + fcb) ----
    if (tid < NN) {
        float acc = fcb[0];
#pragma unroll 1
        for (int c = 0; c < NHID; ++c)
            acc = fmaf(fmaxf(h_b[tid][c], 0.f), fcw[c], acc);
        ((float*)ubuf)[tid] = acc;
    }
    __syncthreads();
    if (tid == 0) {
        float m = -1e30f;
#pragma unroll
        for (int n = 0; n < NN; ++n) m = fmaxf(m, ((float*)ubuf)[n]);
        out[b] = m;
    }
}

extern "C" void kernel_launch(void* const* d_in, const int* in_sizes, int n_in,
                              void* d_out, int out_size, void* d_ws, size_t ws_size,
                              hipStream_t stream) {
    const float* x   = (const float*)d_in[0];
    const float* sup = (const float*)d_in[1];
    const float* wg0 = (const float*)d_in[2];
    const float* bg0 = (const float*)d_in[3];
    const float* wc0 = (const float*)d_in[4];
    const float* bc0 = (const float*)d_in[5];
    const float* wg1 = (const float*)d_in[6];
    const float* bg1 = (const float*)d_in[7];
    const float* wc1 = (const float*)d_in[8];
    const float* bc1 = (const float*)d_in[9];
    const float* fcw = (const float*)d_in[10];
    const float* fcb = (const float*)d_in[11];
    float* out = (float*)d_out;

    // ws: packed fp16 MM1 B-frags + Pcat A-frags (438272 B total)
    char* ws = (char*)d_ws;
    f16x8* wg0p = (f16x8*)(ws + 0);        // KT=3, NTW=40 -> 122880 B
    f16x8* wc0p = (f16x8*)(ws + 122880);   // KT=3, NTW=20 ->  61440 B
    f16x8* wg1p = (f16x8*)(ws + 184320);   // KT=4, NTW=40 -> 163840 B
    f16x8* wc1p = (f16x8*)(ws + 348160);   // KT=4, NTW=20 ->  81920 B
    f16x8* pfp  = (f16x8*)(ws + 430080);   // 8 frags      ->   8192 B

    pack_w<<<dim3(30), dim3(256), 0, stream>>>(wg0, wg0p, 3, 40, 128, 96);
    pack_w<<<dim3(15), dim3(256), 0, stream>>>(wc0, wc0p, 3, 20, 64, 96);
    pack_w<<<dim3(40), dim3(256), 0, stream>>>(wg1, wg1p, 4, 40, 128, 128);
    pack_w<<<dim3(20), dim3(256), 0, stream>>>(wc1, wc1p, 4, 20, 64, 128);
    pack_pcat<<<dim3(1), dim3(512), 0, stream>>>(sup, pfp);

    dcrnn_kernel<<<dim3(NB), dim3(512), 0, stream>>>(
        x, wg0p, bg0, wc0p, bc0, wg1p, bg1, wc1p, bc1, pfp, fcw, fcb, out);
}

// Round 9
// 2434.346 us; speedup vs baseline: 1.6618x; 1.1070x over previous
//
#include <hip/hip_runtime.h>
#include <math.h>

#define NB 512
#define NT 128
#define NN 18
#define NDIM 32
#define NHID 64

typedef _Float16 half_t;
typedef _Float16 f16x4 __attribute__((ext_vector_type(4)));
typedef _Float16 f16x8 __attribute__((ext_vector_type(8)));
typedef float    f32x4 __attribute__((ext_vector_type(4)));

__device__ __forceinline__ float fast_sigmoid(float x) {
    return __builtin_amdgcn_rcpf(1.f + __expf(-x));
}
__device__ __forceinline__ float fast_tanh(float x) {
    float xc = fminf(fmaxf(x, -15.f), 15.f);
    float e  = __expf(2.f * xc);
    return 1.f - 2.f * __builtin_amdgcn_rcpf(e + 1.f);
}
__device__ __forceinline__ f32x4 mfma16(f16x8 a, f16x8 b, f32x4 c) {
    return __builtin_amdgcn_mfma_f32_16x16x32_f16(a, b, c, 0, 0, 0);
}

// ---------------------------------------------------------------------------
// Register-cap model (established r5-r8): launch_bounds arg2 = min BLOCKS/CU;
// cap = 2048 / (arg2 * 8) per wave. We run 1 block/CU (AGPR accumulators push
// the unified total into the 192-granule band no matter what), so the 256-reg
// budget of (512,1) is free headroom. r8 lesson: the compiler REMATERIALIZES
// loop-invariant loads instead of keeping them resident -- VGPR stayed 128
// and the 35 gate loads/step were re-issued with zero prefetch distance.
// Fix: opaque `asm("" : "+v")` defs after the preload make the fragments
// non-rematerializable -> the allocator must carry them in VGPRs.
// ---------------------------------------------------------------------------

// MM1 with persistent B (gate): B held in registers across the whole t-loop.
// SCATTER RULE (race fix): mt=0 writes rows 0..15 (all quads); mt=1 writes
// ONLY quad==0 (rows 16..19). Rows 20..23 / 120..127 stay zero from init.
template <int KT, int CNT, int NCS>
__device__ __forceinline__ void mm1_p(const f16x8 (&B)[CNT][KT],
                                      const half_t* Zf, half_t* Yf,
                                      int nt0, int lane) {
    f16x8 A[2 * KT];
#pragma unroll
    for (int kt = 0; kt < KT; ++kt) {
        A[kt * 2 + 0] = *(const f16x8*)(Zf + (kt * 2 + 0) * 512 + lane * 8);
        A[kt * 2 + 1] = *(const f16x8*)(Zf + (kt * 2 + 1) * 512 + lane * 8);
    }
    const int quad = lane >> 4, ln = lane & 15;
#pragma unroll
    for (int i = 0; i < CNT; ++i) {
        const int ntp = nt0 + i;
        f32x4 ac0 = {0.f, 0.f, 0.f, 0.f};
        f32x4 ac1 = {0.f, 0.f, 0.f, 0.f};
#pragma unroll
        for (int kt = 0; kt < KT; ++kt) {
            ac0 = mfma16(A[kt * 2 + 0], B[i][kt], ac0);
            ac1 = mfma16(A[kt * 2 + 1], B[i][kt], ac1);
        }
        const int m  = ntp >> NCS;            // ncol16 = 1<<NCS
        const int ot = ntp - (m << NCS);
        {
            const int k0 = 24 * m + quad * 4;
            f16x4 pk;
#pragma unroll
            for (int r = 0; r < 4; ++r) pk[r] = (half_t)ac0[r];
            *(f16x4*)(Yf + ((k0 >> 5) * 8 + ot) * 512 +
                      (((((k0 >> 3) & 3) << 4) | ln) * 8) + (k0 & 7)) = pk;
        }
        if (quad == 0) {
            const int k0 = 24 * m + 16;       // multiple of 8
            f16x4 pk;
#pragma unroll
            for (int r = 0; r < 4; ++r) pk[r] = (half_t)ac1[r];
            *(f16x4*)(Yf + ((k0 >> 5) * 8 + ot) * 512 +
                      (((((k0 >> 3) & 3) << 4) | ln) * 8) + (k0 & 7)) = pk;
        }
    }
}

// MM1 streamed (cand): all CNT(<=3) columns loaded upfront within the phase
// (transient regs only).
template <int KT, int CNT, int NCS>
__device__ __forceinline__ void mm1_u(const f16x8* __restrict__ Wf, int NTW,
                                      const half_t* Zf, half_t* Yf,
                                      int nt0, int lane) {
    f16x8 B[CNT][KT];
#pragma unroll
    for (int i = 0; i < CNT; ++i)
#pragma unroll
        for (int kt = 0; kt < KT; ++kt)
            B[i][kt] = Wf[(kt * NTW + nt0 + i) * 64 + lane];
    mm1_p<KT, CNT, NCS>(B, Zf, Yf, nt0, lane);
}

// ---------------------------------------------------------------------------
// MM2 gate: ru(18 x 128) = Pcat(18 x 120pad128) * Ycat + bias -> sigmoid.
// o<64: r -> write r*h into Z frags (kZ = DIMin+o); o>=64: u -> ubuf.
// Does NOT read Zf (safe to write).
// ---------------------------------------------------------------------------
__device__ __forceinline__ void mm2_gate(const half_t* Pc, const half_t* Yf,
                                         half_t* Zf, float bias,
                                         const float (*h)[NHID], float (*ub)[NHID],
                                         int DIMin, int wv, int lane) {
    const int nt2 = wv, quad = lane >> 4, ln = lane & 15;
    f32x4 a0 = {0.f, 0.f, 0.f, 0.f};
    f32x4 a1 = {0.f, 0.f, 0.f, 0.f};
#pragma unroll
    for (int kt = 0; kt < 4; ++kt) {
        f16x8 B  = *(const f16x8*)(Yf + (kt * 8 + nt2) * 512 + lane * 8);
        f16x8 A0 = *(const f16x8*)(Pc + (kt * 2 + 0) * 512 + lane * 8);
        f16x8 A1 = *(const f16x8*)(Pc + (kt * 2 + 1) * 512 + lane * 8);
        a0 = mfma16(A0, B, a0);
        a1 = mfma16(A1, B, a1);
    }
    const int o = nt2 * 16 + ln;
    if (o < NHID) {
        const int kZ = DIMin + o;
        const int base = ((kZ >> 5) * 2) * 512 + (((kZ >> 3) & 3) << 4) * 8 + (kZ & 7);
#pragma unroll
        for (int r = 0; r < 4; ++r) {
            int n = quad * 4 + r;
            float rv = fast_sigmoid(a0[r] + bias);
            Zf[base + (n & 15) * 8] = (half_t)(rv * h[n][o]);
        }
        if (quad == 0) {
#pragma unroll
            for (int r = 0; r < 2; ++r) {
                int n = 16 + r;
                float rv = fast_sigmoid(a1[r] + bias);
                Zf[base + 512 + (n & 15) * 8] = (half_t)(rv * h[n][o]);
            }
        }
    } else {
        const int oc = o - NHID;
#pragma unroll
        for (int r = 0; r < 4; ++r) ub[quad * 4 + r][oc] = fast_sigmoid(a0[r] + bias);
        if (quad == 0) {
#pragma unroll
            for (int r = 0; r < 2; ++r) ub[16 + r][oc] = fast_sigmoid(a1[r] + bias);
        }
    }
}

// ---------------------------------------------------------------------------
// MM2 cand: c = tanh(Pcat * Ycat + bias); h = u*h + (1-u)*c.
// Wave w: nt2 = w&3, mtA = w>>2.
// ---------------------------------------------------------------------------
__device__ __forceinline__ void mm2_cand(const half_t* Pc, const half_t* Yf,
                                         float bias, float (*h)[NHID],
                                         const float (*ub)[NHID], int wv, int lane) {
    const int nt2 = wv & 3, mtA = wv >> 2;
    const int quad = lane >> 4;
    f32x4 a = {0.f, 0.f, 0.f, 0.f};
#pragma unroll
    for (int kt = 0; kt < 4; ++kt) {
        f16x8 B = *(const f16x8*)(Yf + (kt * 8 + nt2) * 512 + lane * 8);
        f16x8 A = *(const f16x8*)(Pc + (kt * 2 + mtA) * 512 + lane * 8);
        a = mfma16(A, B, a);
    }
    const int o = nt2 * 16 + (lane & 15);
#pragma unroll
    for (int r = 0; r < 4; ++r) {
        int n = mtA * 16 + quad * 4 + r;
        if (n < NN) {
            float cv = fast_tanh(a[r] + bias);
            float uv = ub[n][o];
            h[n][o] = uv * h[n][o] + (1.f - uv) * cv;
        }
    }
}

// ---------------------------------------------------------------------------
// Weight pack: W[(m*C + c)][o] fp32 -> MM1 B-frag order fp16.
// ---------------------------------------------------------------------------
__global__ void pack_w(const float* __restrict__ W, f16x8* __restrict__ out,
                       int KT, int NTW, int ncol, int C) {
    int idx = blockIdx.x * blockDim.x + threadIdx.x;
    if (idx >= KT * NTW * 64) return;
    int lane = idx & 63, f = idx >> 6;
    int kt = f / NTW, ntp = f - kt * NTW;
    int ncol16 = ncol >> 4;
    int m = ntp / ncol16, ot = ntp - m * ncol16;
    int o = ot * 16 + (lane & 15);
    f16x8 v;
#pragma unroll
    for (int jj = 0; jj < 8; ++jj) {
        int c = kt * 32 + ((lane >> 4) << 3) + jj;
        v[jj] = (half_t)W[(m * C + c) * ncol + o];
    }
    out[idx] = v;
}

// ---------------------------------------------------------------------------
// Pcat pack: A-frag order fp16 for MM2.
// ---------------------------------------------------------------------------
__global__ void pack_pcat(const float* __restrict__ sup, f16x8* __restrict__ out) {
    int tid = threadIdx.x;                 // 512 threads, 1 block
    int lane = tid & 63, fidx = tid >> 6;  // 8 frags: (kt2, mtA)
    int mtA = fidx & 1, kt2 = fidx >> 1;
    int n = mtA * 16 + (lane & 15);
    f16x8 v;
#pragma unroll 1
    for (int jj = 0; jj < 8; ++jj) {
        int k = kt2 * 32 + ((lane >> 4) << 3) + jj;
        int m = k / 24, j = k - m * 24;
        float val = 0.f;
        if (n < NN && j < NN && m < 5) {
            if (m == 0)      val = (n == j) ? 1.f : 0.f;
            else if (m == 1) val = sup[0 * 324 + n * 18 + j];
            else if (m == 3) val = sup[1 * 324 + n * 18 + j];
            else {
                const float* S = sup + ((m == 2) ? 0 : 1) * 324;
                float acc = 0.f;
                for (int l = 0; l < NN; ++l) acc += S[n * 18 + l] * S[l * 18 + j];
                val = 2.f * acc - ((n == j) ? 1.f : 0.f);
            }
        }
        v[jj] = (half_t)val;
    }
    out[fidx * 64 + lane] = v;
}

// ---------------------------------------------------------------------------
// Persistent per-batch kernel: 512 blocks x 512 threads (8 waves).
// LDS: Zf 8K + Yf 32K + Pc 8K + h_a/h_b/ubuf 13.5K = 62.9K.
// __launch_bounds__(512, 1): unified reg cap 256/wave; occupancy is 2
// waves/SIMD at any allocation in the 129..256 band, so holding Bg0 (60) +
// Bg1 (80) resident is free. asm pins prevent the r8 remat-undo.
// ---------------------------------------------------------------------------
__global__ __launch_bounds__(512, 1) void dcrnn_kernel(
    const float* __restrict__ x,
    const f16x8* __restrict__ wg0, const float* __restrict__ bg0,
    const f16x8* __restrict__ wc0, const float* __restrict__ bc0,
    const f16x8* __restrict__ wg1, const float* __restrict__ bg1,
    const f16x8* __restrict__ wc1, const float* __restrict__ bc1,
    const f16x8* __restrict__ Pf,
    const float* __restrict__ fcw, const float* __restrict__ fcb,
    float* __restrict__ out) {
    __shared__ __align__(16) half_t Zf[8 * 512];    // Z as A-frags (kt*2+mt)
    __shared__ __align__(16) half_t Yf[32 * 512];   // Ycat as B-frags (kt2*8+ot)
    __shared__ __align__(16) half_t Pc[8 * 512];    // Pcat as A-frags
    __shared__ float h_a[NN][NHID];
    __shared__ float h_b[NN][NHID];
    __shared__ float ubuf[NN][NHID];

    const int tid  = threadIdx.x;
    const int lane = tid & 63;
    const int wv   = tid >> 6;
    const int b    = blockIdx.x;

    // one-time init: zero Z/Y frag pads (pad stays zero forever), load Pcat, zero h
    {
        f16x8 z = {0, 0, 0, 0, 0, 0, 0, 0};
        ((f16x8*)Zf)[tid] = z;
#pragma unroll
        for (int i = 0; i < 4; ++i) ((f16x8*)Yf)[tid + i * 512] = z;
        ((f16x8*)Pc)[tid] = Pf[tid];
        for (int i = tid; i < NN * NHID; i += 512) {
            ((float*)h_a)[i] = 0.f;
            ((float*)h_b)[i] = 0.f;
        }
    }

    // mm1 wave partitions: gate NTW=40 -> 5/wave; cand NTW=20 -> 3,3,3,3,2,2,2,2
    const int gnt0 = wv * 5;
    const int cnt0 = (wv < 4) ? wv * 3 : 12 + (wv - 4) * 2;
    const int ln   = lane & 15;

    const float bgt0 = bg0[wv * 16 + ln];
    const float bct0 = bc0[(wv & 3) * 16 + ln];
    const float bgt1 = bg1[wv * 16 + ln];
    const float bct1 = bc1[(wv & 3) * 16 + ln];

    // ---- persistent gate-weight registers (t-invariant) ----
    f16x8 Bg0[5][3];
#pragma unroll
    for (int i = 0; i < 5; ++i)
#pragma unroll
        for (int kt = 0; kt < 3; ++kt)
            Bg0[i][kt] = wg0[(kt * 40 + gnt0 + i) * 64 + lane];
    f16x8 Bg1[5][4];
#pragma unroll
    for (int i = 0; i < 5; ++i)
#pragma unroll
        for (int kt = 0; kt < 4; ++kt)
            Bg1[i][kt] = wg1[(kt * 40 + gnt0 + i) * 64 + lane];
    // Opaque defs: make the fragments non-rematerializable so the allocator
    // CARRIES them instead of re-issuing the loads every t (r8 failure mode).
#pragma unroll
    for (int i = 0; i < 5; ++i)
#pragma unroll
        for (int kt = 0; kt < 3; ++kt)
            asm volatile("" : "+v"(Bg0[i][kt]));
#pragma unroll
    for (int i = 0; i < 5; ++i)
#pragma unroll
        for (int kt = 0; kt < 4; ++kt)
            asm volatile("" : "+v"(Bg1[i][kt]));

    __syncthreads();

    const float* xb = x + (size_t)b * NT * NN * NDIM;

    for (int t = 0; t < NT; ++t) {
        const float* xt = xb + (size_t)t * NN * NDIM;

        // ======== layer 0: C=96 (KT=3), DIMin=32 ========
        // stage A: Zf <- [x | h_a]
        for (int idx = tid; idx < NN * 12; idx += 512) {
            int n = idx / 12, c8 = idx - n * 12;
            int c = c8 * 8;
            const float* src = (c < NDIM) ? &xt[n * NDIM + c] : &h_a[n][c - NDIM];
            f16x8 o8;
#pragma unroll
            for (int q = 0; q < 8; ++q) o8[q] = (half_t)src[q];
            *(f16x8*)(Zf + ((c8 >> 2) * 2 + (n >> 4)) * 512 +
                      (((c8 & 3) << 4) | (n & 15)) * 8) = o8;
        }
        __syncthreads();
        mm1_p<3, 5, 3>(Bg0, Zf, Yf, gnt0, lane);
        __syncthreads();
        mm2_gate(Pc, Yf, Zf, bgt0, h_a, ubuf, 32, wv, lane);
        __syncthreads();
        if (wv < 4) mm1_u<3, 3, 2>(wc0, 20, Zf, Yf, cnt0, lane);
        else        mm1_u<3, 2, 2>(wc0, 20, Zf, Yf, cnt0, lane);
        __syncthreads();
        mm2_cand(Pc, Yf, bct0, h_a, ubuf, wv, lane);
        __syncthreads();

        // ======== layer 1: C=128 (KT=4), DIMin=64 ========
        for (int idx = tid; idx < NN * 16; idx += 512) {
            int n = idx >> 4, c8 = idx & 15;
            int c = c8 * 8;
            const float* src = (c < NHID) ? &h_a[n][c] : &h_b[n][c - NHID];
            f16x8 o8;
#pragma unroll
            for (int q = 0; q < 8; ++q) o8[q] = (half_t)src[q];
            *(f16x8*)(Zf + ((c8 >> 2) * 2 + (n >> 4)) * 512 +
                      (((c8 & 3) << 4) | (n & 15)) * 8) = o8;
        }
        __syncthreads();
        mm1_p<4, 5, 3>(Bg1, Zf, Yf, gnt0, lane);
        __syncthreads();
        mm2_gate(Pc, Yf, Zf, bgt1, h_b, ubuf, 64, wv, lane);
        __syncthreads();
        if (wv < 4) mm1_u<4, 3, 2>(wc1, 20, Zf, Yf, cnt0, lane);
        else        mm1_u<4, 2, 2>(wc1, 20, Zf, Yf, cnt0, lane);
        __syncthreads();
        mm2_cand(Pc, Yf, bct1, h_b, ubuf, wv, lane);
        __syncthreads();
    }

    // ---- output head: out[b] = max_n (relu(h_b[n]) . fcw + fcb) ----
    if (tid < NN) {
        float acc = fcb[0];
#pragma unroll 1
        for (int c = 0; c < NHID; ++c)
            acc = fmaf(fmaxf(h_b[tid][c], 0.f), fcw[c], acc);
        ((float*)ubuf)[tid] = acc;
    }
    __syncthreads();
    if (tid == 0) {
        float m = -1e30f;
#pragma unroll
        for (int n = 0; n < NN; ++n) m = fmaxf(m, ((float*)ubuf)[n]);
        out[b] = m;
    }
}

extern "C" void kernel_launch(void* const* d_in, const int* in_sizes, int n_in,
                              void* d_out, int out_size, void* d_ws, size_t ws_size,
                              hipStream_t stream) {
    const float* x   = (const float*)d_in[0];
    const float* sup = (const float*)d_in[1];
    const float* wg0 = (const float*)d_in[2];
    const float* bg0 = (const float*)d_in[3];
    const float* wc0 = (const float*)d_in[4];
    const float* bc0 = (const float*)d_in[5];
    const float* wg1 = (const float*)d_in[6];
    const float* bg1 = (const float*)d_in[7];
    const float* wc1 = (const float*)d_in[8];
    const float* bc1 = (const float*)d_in[9];
    const float* fcw = (const float*)d_in[10];
    const float* fcb = (const float*)d_in[11];
    float* out = (float*)d_out;

    // ws: packed fp16 MM1 B-frags + Pcat A-frags (438272 B total)
    char* ws = (char*)d_ws;
    f16x8* wg0p = (f16x8*)(ws + 0);        // KT=3, NTW=40 -> 122880 B
    f16x8* wc0p = (f16x8*)(ws + 122880);   // KT=3, NTW=20 ->  61440 B
    f16x8* wg1p = (f16x8*)(ws + 184320);   // KT=4, NTW=40 -> 163840 B
    f16x8* wc1p = (f16x8*)(ws + 348160);   // KT=4, NTW=20 ->  81920 B
    f16x8* pfp  = (f16x8*)(ws + 430080);   // 8 frags      ->   8192 B

    pack_w<<<dim3(30), dim3(256), 0, stream>>>(wg0, wg0p, 3, 40, 128, 96);
    pack_w<<<dim3(15), dim3(256), 0, stream>>>(wc0, wc0p, 3, 20, 64, 96);
    pack_w<<<dim3(40), dim3(256), 0, stream>>>(wg1, wg1p, 4, 40, 128, 128);
    pack_w<<<dim3(20), dim3(256), 0, stream>>>(wc1, wc1p, 4, 20, 64, 128);
    pack_pcat<<<dim3(1), dim3(512), 0, stream>>>(sup, pfp);

    dcrnn_kernel<<<dim3(NB), dim3(512), 0, stream>>>(
        x, wg0p, bg0, wc0p, bc0, wg1p, bg1, wc1p, bc1, pfp, fcw, fcb, out);
}